// Round 5
// baseline (296.261 us; speedup 1.0000x reference)
//
#include <hip/hip_runtime.h>
#include <cmath>

#define S_LEN 2048
#define EMB   1024
#define NHEAD 16
#define DHEAD 64
#define PIT   72   // LDS pitch (ushorts): 144B = 16B-aligned, worst 2-way bank alias (free per m136)

typedef __attribute__((ext_vector_type(8))) short bf16x8;
typedef __attribute__((ext_vector_type(4))) float f32x4;

__device__ __forceinline__ unsigned short f2bf(float f){
    union { float f; unsigned u; } v; v.f = f;
    unsigned r = v.u + 0x7fffu + ((v.u >> 16) & 1u);
    return (unsigned short)(r >> 16);
}

__device__ __forceinline__ unsigned pk2bf(float a, float b){
#if __has_builtin(__builtin_amdgcn_cvt_pk_bf16_f32)
    typedef __attribute__((ext_vector_type(2))) __bf16 bf2;
    bf2 r = __builtin_amdgcn_cvt_pk_bf16_f32(a, b);
    return *(unsigned*)&r;
#else
    return (unsigned)f2bf(a) | ((unsigned)f2bf(b) << 16);
#endif
}

__device__ __forceinline__ float fast_exp2(float x){
#if __has_builtin(__builtin_amdgcn_exp2f)
    return __builtin_amdgcn_exp2f(x);
#else
    return exp2f(x);
#endif
}

__device__ __forceinline__ float fast_rcp(float x){
#if __has_builtin(__builtin_amdgcn_rcpf)
    return __builtin_amdgcn_rcpf(x);
#else
    return 1.0f / x;
#endif
}

// ---------------- fused prep: range-dispatched over blockIdx.x ----------------
// [0,4096):       Q (prescaled exp2-domain) + K -> bf16 [N,H,S,D]
// [4096,5120):    V -> bf16 transposed [N,H,D,S]
// [5120,6144):    W -> bf16
// [6144,14336):   mask int32 -> pair AND-masks [N,Sq,Sk/2] uint (halves 0xFFFF/0)
// [14336,15376):  zero the Op+Lp atomic accumulators (16 MB + 256 KB contiguous)
__global__ void prep_all(const float* __restrict__ q, const float* __restrict__ k,
                         const float* __restrict__ v, const int* __restrict__ mask,
                         const float* __restrict__ W,
                         unsigned short* __restrict__ Qb, unsigned short* __restrict__ Kb,
                         unsigned short* __restrict__ Vt, unsigned short* __restrict__ Wb,
                         unsigned* __restrict__ Mp, float4* __restrict__ Zp){
    __shared__ unsigned short tile[64*68];
    const int b = blockIdx.x, tid = threadIdx.x;
    if (b < 4096){
        const float SC = 0.045084220027780106f;   // log2(e)/32
        int base = (b*256 + tid) * 4;
        int e = base & (EMB - 1);
        int s = (base >> 10) & (S_LEN - 1);
        int n = base >> 21;
        int h = e >> 6, d = e & 63;
        int dst = ((n*NHEAD + h)*S_LEN + s)*DHEAD + d;
        float4 qv = *(const float4*)(q + base);
        float4 kv = *(const float4*)(k + base);
        uint2 qp, kp;
        qp.x = pk2bf(qv.x*SC, qv.y*SC);
        qp.y = pk2bf(qv.z*SC, qv.w*SC);
        kp.x = pk2bf(kv.x, kv.y);
        kp.y = pk2bf(kv.z, kv.w);
        *(uint2*)(Qb + dst) = qp;
        *(uint2*)(Kb + dst) = kp;
    } else if (b < 5120){
        int idx = b - 4096;
        int st = idx & 31, h = (idx >> 5) & 15, n = idx >> 9;
        int sbase = st * 64;
#pragma unroll
        for (int i = 0; i < 4; i++){
            int c = tid + i*256;
            int srow = c >> 4, c4 = (c & 15) * 4;
            float4 x = *(const float4*)(v + (n*S_LEN + sbase + srow)*EMB + h*DHEAD + c4);
            uint2 p;
            p.x = pk2bf(x.x, x.y);
            p.y = pk2bf(x.z, x.w);
            *(uint2*)&tile[srow*68 + c4] = p;
        }
        __syncthreads();
#pragma unroll
        for (int i = 0; i < 2; i++){
            int c = tid + i*256;
            int d = c >> 3, s8 = (c & 7) * 8;
            unsigned u0 = (unsigned)tile[(s8+0)*68 + d] | ((unsigned)tile[(s8+1)*68 + d] << 16);
            unsigned u1 = (unsigned)tile[(s8+2)*68 + d] | ((unsigned)tile[(s8+3)*68 + d] << 16);
            unsigned u2 = (unsigned)tile[(s8+4)*68 + d] | ((unsigned)tile[(s8+5)*68 + d] << 16);
            unsigned u3 = (unsigned)tile[(s8+6)*68 + d] | ((unsigned)tile[(s8+7)*68 + d] << 16);
            uint4 pk; pk.x = u0; pk.y = u1; pk.z = u2; pk.w = u3;
            *(uint4*)(Vt + ((n*NHEAD + h)*DHEAD + d)*S_LEN + sbase + s8) = pk;
        }
    } else if (b < 6144){
        int base = ((b - 5120)*256 + tid) * 4;
        float4 x = *(const float4*)(W + base);
        uint2 p;
        p.x = pk2bf(x.x, x.y);
        p.y = pk2bf(x.z, x.w);
        *(uint2*)(Wb + base) = p;
    } else if (b < 14336){
        int u = (b - 6144)*256 + tid;                 // one int4 -> one uint2
        int4 m = ((const int4*)mask)[u];
        uint2 o;
        o.x = (m.x ? 0xFFFFu : 0u) | (m.y ? 0xFFFF0000u : 0u);
        o.y = (m.z ? 0xFFFFu : 0u) | (m.w ? 0xFFFF0000u : 0u);
        *(uint2*)(Mp + u*2) = o;
    } else {
        int base = (b - 14336)*1024 + tid;            // float4 units; 1040*1024 covers 16.25 MB
        float4 z = {0.f, 0.f, 0.f, 0.f};
#pragma unroll
        for (int i = 0; i < 4; i++)
            Zp[base + i*256] = z;
    }
}

// ---------------- flash attention v3: rt=4, V-frags direct from global ----------------
// grid (qt=8, h+16*split=32, n=2) = 512 blocks (2/CU), block 256 (4 waves).
// Wave owns 64 q-rows; K-tile 64. LDS = K stage (9 KB) + per-wave P (36 KB) only:
// per-wave-iter LDS ops drop 24b128+8b64 -> 18b128+16b64 (per-q cost 10.5 -> ~5),
// attacking the measured CU-shared LDS-pipe wall (~5700 cyc/CU-iter in r4).
// V B-fragments load straight from Vt [N,H,D,S] (16B chunks, L1/L2-hot, barrier-synced).
__global__ __launch_bounds__(256, 2) void flash_attn(
    const unsigned short* __restrict__ Qb, const unsigned short* __restrict__ Kb,
    const unsigned short* __restrict__ Vt, const unsigned* __restrict__ Mp,
    float* __restrict__ Op, float* __restrict__ Lp){
    __shared__ unsigned short Kt[64*PIT];
    __shared__ unsigned short Pt[4][64*PIT];

    const int n = blockIdx.z;
    const int qt = blockIdx.x;
    const int h = blockIdx.y & 15, split = blockIdx.y >> 4;
    const int tid = threadIdx.x;
    const int wave = tid >> 6, lane = tid & 63, il = lane & 15, quad = lane >> 4;
    const int qbase = qt*256 + wave*64;
    const int kbase = split*1024;

    const unsigned short* Qh = Qb + (n*NHEAD + h)*S_LEN*DHEAD;
    const unsigned short* Kh = Kb + (n*NHEAD + h)*S_LEN*DHEAD + kbase*DHEAD;
    const unsigned short* Vh = Vt + (n*NHEAD + h)*DHEAD*S_LEN + kbase;
    // pair-mask row base (per-lane): row q = qbase + rt*16 + il
    const unsigned* mpb = Mp + (size_t)(n*S_LEN + qbase + il)*(S_LEN/2) + (kbase >> 1) + quad*2;

    // staging chunk owned by this thread (rows srow, srow+32; 16B at scol)
    const int srow = tid >> 3, scol = (tid & 7)*8;

    bf16x8 Qf[4][2];   // B-operand frags: n=il -> q row, k = quad*8+j -> d
#pragma unroll
    for (int rt = 0; rt < 4; rt++)
#pragma unroll
        for (int ks = 0; ks < 2; ks++)
            Qf[rt][ks] = *(const bf16x8*)(Qh + (qbase + rt*16 + il)*DHEAD + ks*32 + quad*8);

    f32x4 acc[4][4], accL[4];
#pragma unroll
    for (int rt = 0; rt < 4; rt++){
        accL[rt] = (f32x4){0.f,0.f,0.f,0.f};
#pragma unroll
        for (int j = 0; j < 4; j++) acc[rt][j] = (f32x4){0.f,0.f,0.f,0.f};
    }
    const short onev = 0x3F80;   // bf16 1.0
    const bf16x8 onesb = {onev,onev,onev,onev,onev,onev,onev,onev};

    unsigned short* Pw = Pt[wave];

    // prefetch K tile 0 into registers
    uint4 kpre0 = *(const uint4*)(Kh + srow*DHEAD + scol);
    uint4 kpre1 = *(const uint4*)(Kh + (srow + 32)*DHEAD + scol);

    for (int kb = 0; kb < 1024; kb += 64){
        // drain K prefetch into LDS
        *(uint4*)&Kt[srow*PIT + scol]        = kpre0;
        *(uint4*)&Kt[(srow + 32)*PIT + scol] = kpre1;
        __syncthreads();
        // V fragments for THIS tile: direct global (consumed ~1500 cyc later at PV)
        uint4 vf[2][4];
#pragma unroll
        for (int kk = 0; kk < 2; kk++)
#pragma unroll
            for (int dt = 0; dt < 4; dt++)
                vf[kk][dt] = *(const uint4*)(Vh + (dt*16 + il)*S_LEN + kb + kk*32 + quad*8);
        // K prefetch for next tile
        if (kb + 64 < 1024){
            kpre0 = *(const uint4*)(Kh + (kb + 64 + srow)*DHEAD + scol);
            kpre1 = *(const uint4*)(Kh + (kb + 64 + srow + 32)*DHEAD + scol);
        }

        // K fragments once (reused across 4 rt)
        bf16x8 Kf[4][2];
#pragma unroll
        for (int t = 0; t < 4; t++)
#pragma unroll
            for (int ks = 0; ks < 2; ks++)
                Kf[t][ks] = *(const bf16x8*)(&Kt[(t*16 + il)*PIT + ks*32 + quad*8]);

        // E^T = K.Q^T per rt; p = exp2(e) & pair-mask; pack to Pw
#pragma unroll
        for (int rt = 0; rt < 4; rt++){
            f32x4 e[4];
#pragma unroll
            for (int t = 0; t < 4; t++){
                f32x4 z = (f32x4){0.f,0.f,0.f,0.f};
                z    = __builtin_amdgcn_mfma_f32_16x16x32_bf16(Kf[t][0], Qf[rt][0], z, 0, 0, 0);
                e[t] = __builtin_amdgcn_mfma_f32_16x16x32_bf16(Kf[t][1], Qf[rt][1], z, 0, 0, 0);
            }
            const unsigned* mp = mpb + rt*16*(S_LEN/2) + (kb >> 1);
#pragma unroll
            for (int t = 0; t < 4; t++){
                uint2 mw = *(const uint2*)(mp + t*8);
                float p0 = fast_exp2(e[t][0]);
                float p1 = fast_exp2(e[t][1]);
                float p2 = fast_exp2(e[t][2]);
                float p3 = fast_exp2(e[t][3]);
                uint2 pk;
                pk.x = pk2bf(p0, p1) & mw.x;
                pk.y = pk2bf(p2, p3) & mw.y;
                *(uint2*)&Pw[(rt*16 + il)*PIT + t*16 + quad*4] = pk;
            }
        }
        // PV: O += P.V ; l += P.1
#pragma unroll
        for (int kk = 0; kk < 2; kk++){
            bf16x8 Pa[4];
#pragma unroll
            for (int rt = 0; rt < 4; rt++){
                Pa[rt] = *(const bf16x8*)(&Pw[(rt*16 + il)*PIT + kk*32 + quad*8]);
                accL[rt] = __builtin_amdgcn_mfma_f32_16x16x32_bf16(Pa[rt], onesb, accL[rt], 0, 0, 0);
            }
#pragma unroll
            for (int dt = 0; dt < 4; dt++){
                bf16x8 Vfr = *(const bf16x8*)&vf[kk][dt];
#pragma unroll
                for (int rt = 0; rt < 4; rt++)
                    acc[rt][dt] = __builtin_amdgcn_mfma_f32_16x16x32_bf16(Pa[rt], Vfr, acc[rt][dt], 0, 0, 0);
            }
        }
        __syncthreads();
    }

    // epilogue: accumulate unnormalized O partial + l partial (atomic; 2 splits commute)
#pragma unroll
    for (int rt = 0; rt < 4; rt++){
#pragma unroll
        for (int dt = 0; dt < 4; dt++)
#pragma unroll
            for (int r = 0; r < 4; r++){
                size_t row = (size_t)(n*S_LEN + qbase + rt*16 + quad*4 + r);
                atomicAdd(&Op[row*EMB + h*DHEAD + dt*16 + il], acc[rt][dt][r]);
            }
        if (il == 0){
#pragma unroll
            for (int r = 0; r < 4; r++)
                atomicAdd(&Lp[(n*NHEAD + h)*S_LEN + qbase + rt*16 + quad*4 + r], accL[rt][r]);
        }
    }
}

// ---------------- normalize -> bf16 AttO [N*S, EMB] ----------------
__global__ void merge_norm(const float* __restrict__ Op, const float* __restrict__ Lp,
                           unsigned short* __restrict__ AttO){
    int idx = blockIdx.x*256 + threadIdx.x;       // 4096 rows x 256 float4-chunks
    int row = idx >> 8, c4 = (idx & 255)*4;
    int n = row >> 11, q = row & (S_LEN-1), h = c4 >> 6;
    float4 o = *(const float4*)(Op + (size_t)row*EMB + c4);
    float l = Lp[(n*NHEAD + h)*S_LEN + q];
    float inv = fast_rcp(l);
    uint2 p;
    p.x = pk2bf(o.x*inv, o.y*inv);
    p.y = pk2bf(o.z*inv, o.w*inv);
    *(uint2*)(AttO + (size_t)row*EMB + c4) = p;
}

// ---------------- output GEMM: out[4096,1024] = A.W^T + b, 128x128 tiles ----------------
__global__ __launch_bounds__(256, 1) void gemm_out(
    const unsigned short* __restrict__ A, const unsigned short* __restrict__ W,
    const float* __restrict__ bias, float* __restrict__ out){
    __shared__ unsigned short At[128*PIT];
    __shared__ unsigned short Wt[128*PIT];
    const int nb = blockIdx.x, mb = blockIdx.y;
    const int tid = threadIdx.x;
    const int wave = tid >> 6, lane = tid & 63, il = lane & 15, quad = lane >> 4;
    const int wm = wave & 1, wn = wave >> 1;
    const int mbase = mb*128, nbase = nb*128;
    const int arow = tid >> 3, acol = (tid & 7)*8;   // rows arow+{0,32,64,96}

    f32x4 acc[4][4];
#pragma unroll
    for (int i = 0; i < 4; i++)
#pragma unroll
        for (int j = 0; j < 4; j++) acc[i][j] = (f32x4){0.f,0.f,0.f,0.f};

    uint4 apre[4], wpre[4];
#pragma unroll
    for (int j = 0; j < 4; j++){
        apre[j] = *(const uint4*)(A + (size_t)(mbase + arow + j*32)*EMB + acol);
        wpre[j] = *(const uint4*)(W + (size_t)(nbase + arow + j*32)*EMB + acol);
    }

    for (int kb = 0; kb < EMB; kb += 64){
#pragma unroll
        for (int j = 0; j < 4; j++){
            *(uint4*)&At[(arow + j*32)*PIT + acol] = apre[j];
            *(uint4*)&Wt[(arow + j*32)*PIT + acol] = wpre[j];
        }
        __syncthreads();
        if (kb + 64 < EMB){
#pragma unroll
            for (int j = 0; j < 4; j++){
                apre[j] = *(const uint4*)(A + (size_t)(mbase + arow + j*32)*EMB + kb + 64 + acol);
                wpre[j] = *(const uint4*)(W + (size_t)(nbase + arow + j*32)*EMB + kb + 64 + acol);
            }
        }
#pragma unroll
        for (int ks = 0; ks < 2; ks++){
            bf16x8 Af[4], Wf[4];
#pragma unroll
            for (int mt = 0; mt < 4; mt++)
                Af[mt] = *(const bf16x8*)(&At[(wm*64 + mt*16 + il)*PIT + ks*32 + quad*8]);
#pragma unroll
            for (int nt = 0; nt < 4; nt++)
                Wf[nt] = *(const bf16x8*)(&Wt[(wn*64 + nt*16 + il)*PIT + ks*32 + quad*8]);
#pragma unroll
            for (int mt = 0; mt < 4; mt++)
#pragma unroll
                for (int nt = 0; nt < 4; nt++)
                    acc[mt][nt] = __builtin_amdgcn_mfma_f32_16x16x32_bf16(Af[mt], Wf[nt], acc[mt][nt], 0, 0, 0);
        }
        __syncthreads();
    }
    float bb[4];
#pragma unroll
    for (int nt = 0; nt < 4; nt++) bb[nt] = bias[nbase + wn*64 + nt*16 + il];
#pragma unroll
    for (int mt = 0; mt < 4; mt++)
#pragma unroll
        for (int nt = 0; nt < 4; nt++)
#pragma unroll
            for (int r = 0; r < 4; r++){
                int row = mbase + wm*64 + mt*16 + quad*4 + r;
                int col = nbase + wn*64 + nt*16 + il;
                out[(size_t)row*EMB + col] = acc[mt][nt][r] + bb[nt];
            }
}

extern "C" void kernel_launch(void* const* d_in, const int* in_sizes, int n_in,
                              void* d_out, int out_size, void* d_ws, size_t ws_size,
                              hipStream_t stream){
    const float* values = (const float*)d_in[0];
    const float* keys   = (const float*)d_in[1];
    const float* query  = (const float*)d_in[2];
    const int*   mask   = (const int*)d_in[3];
    const float* W_fc   = (const float*)d_in[4];
    const float* b_fc   = (const float*)d_in[5];
    float* out = (float*)d_out;

    char* ws = (char*)d_ws;
    unsigned short* Qb  = (unsigned short*)(ws);                        // 8 MB
    unsigned short* Kb  = (unsigned short*)(ws + (8ull  << 20));        // 8 MB
    unsigned short* Vtb = (unsigned short*)(ws + (16ull << 20));        // 8 MB
    unsigned short* Wb  = (unsigned short*)(ws + (24ull << 20));        // 2 MB
    unsigned*       Mp  = (unsigned*)      (ws + (26ull << 20));        // 16 MB
    float*          Opf = (float*)         (ws + (42ull << 20));        // 16 MB (fp32 O accum)
    float*          Lpf = (float*)         (ws + (58ull << 20));        // 256 KB (l accum)
    unsigned short* AttO= (unsigned short*)(ws + (58ull << 20) + (512ull << 10)); // 8 MB -> 66.5 MB total

    prep_all  <<<15376, 256, 0, stream>>>(query, keys, values, mask, W_fc,
                                          Qb, Kb, Vtb, Wb, Mp, (float4*)Opf);
    flash_attn<<<dim3(8, 32, 2), 256, 0, stream>>>(Qb, Kb, Vtb, Mp, Opf, Lpf);
    merge_norm<<<4096, 256, 0, stream>>>(Opf, Lpf, AttO);
    gemm_out  <<<dim3(8, 32), 256, 0, stream>>>(AttO, Wb, b_fc, out);
}

// Round 6
// 282.487 us; speedup vs baseline: 1.0488x; 1.0488x over previous
//
#include <hip/hip_runtime.h>
#include <cmath>

#define S_LEN 2048
#define EMB   1024
#define NHEAD 16
#define DHEAD 64

typedef __attribute__((ext_vector_type(8))) short bf16x8;
typedef __attribute__((ext_vector_type(4))) float f32x4;

__device__ __forceinline__ unsigned short f2bf(float f){
    union { float f; unsigned u; } v; v.f = f;
    unsigned r = v.u + 0x7fffu + ((v.u >> 16) & 1u);
    return (unsigned short)(r >> 16);
}

__device__ __forceinline__ unsigned pk2bf(float a, float b){
#if __has_builtin(__builtin_amdgcn_cvt_pk_bf16_f32)
    typedef __attribute__((ext_vector_type(2))) __bf16 bf2;
    bf2 r = __builtin_amdgcn_cvt_pk_bf16_f32(a, b);
    return *(unsigned*)&r;
#else
    return (unsigned)f2bf(a) | ((unsigned)f2bf(b) << 16);
#endif
}

__device__ __forceinline__ float fast_exp2(float x){
#if __has_builtin(__builtin_amdgcn_exp2f)
    return __builtin_amdgcn_exp2f(x);
#else
    return exp2f(x);
#endif
}

__device__ __forceinline__ float fast_rcp(float x){
#if __has_builtin(__builtin_amdgcn_rcpf)
    return __builtin_amdgcn_rcpf(x);
#else
    return 1.0f / x;
#endif
}

// ---------------- fused prep: range-dispatched over blockIdx.x ----------------
// [0,4096):       Q -> bf16 [N,H,S,D] (prescaled exp2-domain); K -> FRAGMENT order:
//                 per (n,h): [slab=s>>4 (128)][ks=d>>5 (2)][lane=((d>>3)&3)*16+(s&15)][j=d&7]
// [4096,5120):    V -> FRAGMENT order: per (n,h): [kt=s>>6 (32)][dt(4)][kk(2)][lane][j]
//                 element = V[kt*64 + kk*32 + quad*8 + j][h*64 + dt*16 + il]
// [5120,6144):    W -> bf16
// [6144,14336):   mask int32 -> pair AND-masks [N,Sq,Sk/2] uint (halves 0xFFFF/0)
// [14336,15376):  zero the Op+Lp atomic accumulators (16 MB + 256 KB contiguous)
__global__ void prep_all(const float* __restrict__ q, const float* __restrict__ k,
                         const float* __restrict__ v, const int* __restrict__ mask,
                         const float* __restrict__ W,
                         unsigned short* __restrict__ Qb, unsigned short* __restrict__ Kb,
                         unsigned short* __restrict__ Vt, unsigned short* __restrict__ Wb,
                         unsigned* __restrict__ Mp, float4* __restrict__ Zp){
    __shared__ unsigned short tile[64*68];
    const int b = blockIdx.x, tid = threadIdx.x;
    if (b < 4096){
        const float SC = 0.045084220027780106f;   // log2(e)/32
        int base = (b*256 + tid) * 4;
        int e = base & (EMB - 1);
        int s = (base >> 10) & (S_LEN - 1);
        int n = base >> 21;
        int h = e >> 6, d = e & 63;
        float4 qv = *(const float4*)(q + base);
        float4 kv = *(const float4*)(k + base);
        uint2 qp, kp;
        qp.x = pk2bf(qv.x*SC, qv.y*SC);
        qp.y = pk2bf(qv.z*SC, qv.w*SC);
        kp.x = pk2bf(kv.x, kv.y);
        kp.y = pk2bf(kv.z, kv.w);
        *(uint2*)(Qb + ((size_t)((n*NHEAD + h)*S_LEN + s))*DHEAD + d) = qp;
        // K fragment order
        int slab = s >> 4, sil = s & 15;
        int ks = d >> 5, qd = (d >> 3) & 3, j = d & 7;
        size_t koff = ((size_t)((n*NHEAD + h)*128 + slab))*1024 + ks*512 + (qd*16 + sil)*8 + j;
        *(uint2*)(Kb + koff) = kp;
    } else if (b < 5120){
        int idx = b - 4096;
        int st = idx & 31, h = (idx >> 5) & 15, n = idx >> 9;
        int sbase = st * 64;
#pragma unroll
        for (int i = 0; i < 4; i++){
            int c = tid + i*256;
            int srow = c >> 4, c4 = (c & 15) * 4;
            float4 x = *(const float4*)(v + (n*S_LEN + sbase + srow)*EMB + h*DHEAD + c4);
            uint2 p;
            p.x = pk2bf(x.x, x.y);
            p.y = pk2bf(x.z, x.w);
            *(uint2*)&tile[srow*68 + c4] = p;
        }
        __syncthreads();
        unsigned short* Vh = Vt + ((size_t)((n*NHEAD + h)*32 + st))*4096;
#pragma unroll
        for (int i = 0; i < 2; i++){
            int c = tid + i*256;            // 0..511 chunks of 16B
            int ln = c & 63, dk = c >> 6;   // dk = dt*2+kk
            int dt = dk >> 1, kk = dk & 1;
            int q2 = ln >> 4, i2 = ln & 15;
            int colb = dt*16 + i2;
            int rowb = kk*32 + q2*8;
            unsigned u0 = (unsigned)tile[(rowb+0)*68 + colb] | ((unsigned)tile[(rowb+1)*68 + colb] << 16);
            unsigned u1 = (unsigned)tile[(rowb+2)*68 + colb] | ((unsigned)tile[(rowb+3)*68 + colb] << 16);
            unsigned u2 = (unsigned)tile[(rowb+4)*68 + colb] | ((unsigned)tile[(rowb+5)*68 + colb] << 16);
            unsigned u3 = (unsigned)tile[(rowb+6)*68 + colb] | ((unsigned)tile[(rowb+7)*68 + colb] << 16);
            uint4 pk; pk.x = u0; pk.y = u1; pk.z = u2; pk.w = u3;
            *(uint4*)(Vh + c*8) = pk;
        }
    } else if (b < 6144){
        int base = ((b - 5120)*256 + tid) * 4;
        float4 x = *(const float4*)(W + base);
        uint2 p;
        p.x = pk2bf(x.x, x.y);
        p.y = pk2bf(x.z, x.w);
        *(uint2*)(Wb + base) = p;
    } else if (b < 14336){
        int u = (b - 6144)*256 + tid;                 // one int4 -> one uint2
        int4 m = ((const int4*)mask)[u];
        uint2 o;
        o.x = (m.x ? 0xFFFFu : 0u) | (m.y ? 0xFFFF0000u : 0u);
        o.y = (m.z ? 0xFFFFu : 0u) | (m.w ? 0xFFFF0000u : 0u);
        *(uint2*)(Mp + u*2) = o;
    } else {
        int base = (b - 14336)*1024 + tid;            // float4 units
        float4 z = {0.f, 0.f, 0.f, 0.f};
#pragma unroll
        for (int i = 0; i < 4; i++)
            Zp[base + i*256] = z;
    }
}

// ---------------- flash attention v4: BARRIER-FREE, fragment-direct K/V ----------------
// grid (qt=16, h+16*split=32, n=2) = 1024 blocks, 256 thr (4 waves), 16 waves/CU.
// K and V fragments load straight from global in fragment order (1KB coalesced dwordx4);
// no K/V LDS staging, zero __syncthreads — waves drift freely, TLP hides L2 latency
// (r3-r5 all latency-bound: every pipe <40% while iters marched in barrier lockstep).
// LDS = per-wave P round-trip only, XOR-swizzled (row*64 + ((col/8)^(row&7))*8):
// provably even bank coverage -> conflicts ~0 (r4's 7.3e6 was PIT=72's 4-way alias).
__global__ __launch_bounds__(256, 4) void flash_attn(
    const unsigned short* __restrict__ Qb, const unsigned short* __restrict__ Kfr,
    const unsigned short* __restrict__ Vfr, const unsigned* __restrict__ Mp,
    float* __restrict__ Op, float* __restrict__ Lp){
    __shared__ unsigned short Pt[4][32*64];

    const int n = blockIdx.z, qt = blockIdx.x;
    const int h = blockIdx.y & 15, split = blockIdx.y >> 4;
    const int tid = threadIdx.x;
    const int wave = tid >> 6, lane = tid & 63, il = lane & 15, quad = lane >> 4;
    const int qbase = qt*128 + wave*32;
    const int kbase = split*1024;
    const int swz = il & 7;                     // row-dependent xor term (row&7 == il&7 here)

    const unsigned short* Qh = Qb + (size_t)(n*NHEAD + h)*S_LEN*DHEAD;
    const unsigned short* Kh = Kfr + (size_t)(n*NHEAD + h)*S_LEN*DHEAD + (size_t)kbase*DHEAD + lane*8;
    const unsigned short* Vh = Vfr + (size_t)(n*NHEAD + h)*S_LEN*DHEAD + (size_t)kbase*DHEAD + lane*8;
    const unsigned* mp0 = Mp + (size_t)(n*S_LEN + qbase + il)*(S_LEN/2) + (kbase >> 1) + quad*2;
    const unsigned* mp1 = mp0 + 16*(S_LEN/2);

    bf16x8 Qf[2][2];   // B-operand: n=il -> q row, k=quad*8+j -> d
#pragma unroll
    for (int rt = 0; rt < 2; rt++)
#pragma unroll
        for (int ks = 0; ks < 2; ks++)
            Qf[rt][ks] = *(const bf16x8*)(Qh + (qbase + rt*16 + il)*DHEAD + ks*32 + quad*8);

    f32x4 acc[2][4], accL[2];
#pragma unroll
    for (int rt = 0; rt < 2; rt++){
        accL[rt] = (f32x4){0.f,0.f,0.f,0.f};
#pragma unroll
        for (int j = 0; j < 4; j++) acc[rt][j] = (f32x4){0.f,0.f,0.f,0.f};
    }
    const short onev = 0x3F80;   // bf16 1.0
    const bf16x8 onesb = {onev,onev,onev,onev,onev,onev,onev,onev};

    unsigned short* Pw = Pt[wave];
    // P write slot: row = rt*16+il, cols t*16+quad*4 (b64); swizzled
    const int pw_base = (il << 6) + ((quad & 1) << 2);
    const int pw_qhi  = quad >> 1;
    // P read slot: row = rt*16+il, cols kk*32+quad*8 (b128); swizzled
    const int pr_base = (il << 6);

    for (int kb = 0; kb < 1024; kb += 64){
        const unsigned short* Kt = Kh + kb*64;
        const unsigned short* Vt = Vh + kb*64;
        const unsigned* mk0 = mp0 + (kb >> 1);
        const unsigned* mk1 = mp1 + (kb >> 1);

        // QK^T per 16-k slab t: E^T = K.Q^T (A = K frags from global, B = Q regs)
        // C layout: col=il -> q, row=quad*4+r -> k
#pragma unroll
        for (int t = 0; t < 4; t++){
            bf16x8 kf0 = *(const bf16x8*)(Kt + t*1024);
            bf16x8 kf1 = *(const bf16x8*)(Kt + t*1024 + 512);
            f32x4 z0 = (f32x4){0.f,0.f,0.f,0.f};
            z0 = __builtin_amdgcn_mfma_f32_16x16x32_bf16(kf0, Qf[0][0], z0, 0, 0, 0);
            f32x4 e0 = __builtin_amdgcn_mfma_f32_16x16x32_bf16(kf1, Qf[0][1], z0, 0, 0, 0);
            f32x4 z1 = (f32x4){0.f,0.f,0.f,0.f};
            z1 = __builtin_amdgcn_mfma_f32_16x16x32_bf16(kf0, Qf[1][0], z1, 0, 0, 0);
            f32x4 e1 = __builtin_amdgcn_mfma_f32_16x16x32_bf16(kf1, Qf[1][1], z1, 0, 0, 0);
            uint2 mw0 = *(const uint2*)(mk0 + t*8);
            uint2 mw1 = *(const uint2*)(mk1 + t*8);
            // p = exp2(e) & pair-mask (x*{1,0} == x&{0xFFFF,0}); pack 4 consecutive k
            uint2 pk0, pk1;
            pk0.x = pk2bf(fast_exp2(e0[0]), fast_exp2(e0[1])) & mw0.x;
            pk0.y = pk2bf(fast_exp2(e0[2]), fast_exp2(e0[3])) & mw0.y;
            pk1.x = pk2bf(fast_exp2(e1[0]), fast_exp2(e1[1])) & mw1.x;
            pk1.y = pk2bf(fast_exp2(e1[2]), fast_exp2(e1[3])) & mw1.y;
            int blk = ((t*2 + pw_qhi) ^ swz) << 3;
            *(uint2*)&Pw[pw_base + blk]          = pk0;
            *(uint2*)&Pw[(16 << 6) + pw_base + blk] = pk1;
        }
        // PV: O += P.V ; l += P.1  (V frags direct from global, A=P from swizzled LDS)
#pragma unroll
        for (int kk = 0; kk < 2; kk++){
            int rblk = (((kk*4 + quad) ^ swz) << 3);
            bf16x8 Pa0 = *(const bf16x8*)&Pw[pr_base + rblk];
            bf16x8 Pa1 = *(const bf16x8*)&Pw[(16 << 6) + pr_base + rblk];
            accL[0] = __builtin_amdgcn_mfma_f32_16x16x32_bf16(Pa0, onesb, accL[0], 0, 0, 0);
            accL[1] = __builtin_amdgcn_mfma_f32_16x16x32_bf16(Pa1, onesb, accL[1], 0, 0, 0);
#pragma unroll
            for (int dt = 0; dt < 4; dt++){
                bf16x8 Vf = *(const bf16x8*)(Vt + (dt*2 + kk)*512);
                acc[0][dt] = __builtin_amdgcn_mfma_f32_16x16x32_bf16(Pa0, Vf, acc[0][dt], 0, 0, 0);
                acc[1][dt] = __builtin_amdgcn_mfma_f32_16x16x32_bf16(Pa1, Vf, acc[1][dt], 0, 0, 0);
            }
        }
        // no barrier: P buffers are wave-private
    }

    // epilogue: accumulate unnormalized O partial + l partial (atomic; 2 splits commute)
#pragma unroll
    for (int rt = 0; rt < 2; rt++){
#pragma unroll
        for (int dt = 0; dt < 4; dt++)
#pragma unroll
            for (int r = 0; r < 4; r++){
                size_t row = (size_t)(n*S_LEN + qbase + rt*16 + quad*4 + r);
                atomicAdd(&Op[row*EMB + h*DHEAD + dt*16 + il], acc[rt][dt][r]);
            }
        if (il == 0){
#pragma unroll
            for (int r = 0; r < 4; r++)
                atomicAdd(&Lp[(n*NHEAD + h)*S_LEN + qbase + rt*16 + quad*4 + r], accL[rt][r]);
        }
    }
}

// ---------------- fused normalize + output GEMM: out = (Op/l).W^T + b ----------------
// 128M x 64N tiles, BK=64 (h = kb>>6 iter-constant). A-staging normalizes fp32 Op by
// rcp(l) and packs bf16 on the fly. Swizzled LDS (no pad, conflict-free), 4 blocks/CU.
__global__ __launch_bounds__(256, 4) void gemm_norm(
    const float* __restrict__ Op, const float* __restrict__ Lp,
    const unsigned short* __restrict__ W, const float* __restrict__ bias,
    float* __restrict__ out){
    __shared__ unsigned short At[128*64];
    __shared__ unsigned short Wt[64*64];
    const int nb = blockIdx.x, mb = blockIdx.y;
    const int tid = threadIdx.x;
    const int wave = tid >> 6, lane = tid & 63, il = lane & 15, quad = lane >> 4;
    const int wm = wave & 1, wn = wave >> 1;
    const int mbase = mb*128, nbase = nb*64;
    const int arow = tid >> 3, ab8 = tid & 7;         // staging: row arow+j*32, col ab8*8
    const int sblk = (ab8 ^ (arow & 7)) << 3;         // swizzled staging col offset
    const int n_blk = mbase >> 11, qoff = (mbase & (S_LEN-1));
    const float* Lb = Lp + n_blk*NHEAD*S_LEN + qoff;

    f32x4 acc[4][2];
#pragma unroll
    for (int i = 0; i < 4; i++)
#pragma unroll
        for (int j = 0; j < 2; j++) acc[i][j] = (f32x4){0.f,0.f,0.f,0.f};

    float4 apre[4][2]; float lpre[4]; uint4 wpre[2];
#pragma unroll
    for (int j = 0; j < 4; j++){
        const float* src = Op + (size_t)(mbase + arow + j*32)*EMB + ab8*8;
        apre[j][0] = *(const float4*)(src);
        apre[j][1] = *(const float4*)(src + 4);
        lpre[j] = Lb[arow + j*32];           // h = 0 at kb = 0
    }
#pragma unroll
    for (int j = 0; j < 2; j++)
        wpre[j] = *(const uint4*)(W + (size_t)(nbase + arow + j*32)*EMB + ab8*8);

    for (int kb = 0; kb < EMB; kb += 64){
#pragma unroll
        for (int j = 0; j < 4; j++){
            float inv = fast_rcp(lpre[j]);
            uint4 pk;
            pk.x = pk2bf(apre[j][0].x*inv, apre[j][0].y*inv);
            pk.y = pk2bf(apre[j][0].z*inv, apre[j][0].w*inv);
            pk.z = pk2bf(apre[j][1].x*inv, apre[j][1].y*inv);
            pk.w = pk2bf(apre[j][1].z*inv, apre[j][1].w*inv);
            *(uint4*)&At[((arow + j*32) << 6) + sblk] = pk;
        }
#pragma unroll
        for (int j = 0; j < 2; j++)
            *(uint4*)&Wt[((arow + j*32) << 6) + sblk] = wpre[j];
        __syncthreads();
        if (kb + 64 < EMB){
            int h = (kb + 64) >> 6;
#pragma unroll
            for (int j = 0; j < 4; j++){
                const float* src = Op + (size_t)(mbase + arow + j*32)*EMB + kb + 64 + ab8*8;
                apre[j][0] = *(const float4*)(src);
                apre[j][1] = *(const float4*)(src + 4);
                lpre[j] = Lb[h*S_LEN + arow + j*32];
            }
#pragma unroll
            for (int j = 0; j < 2; j++)
                wpre[j] = *(const uint4*)(W + (size_t)(nbase + arow + j*32)*EMB + kb + 64 + ab8*8);
        }
#pragma unroll
        for (int ks = 0; ks < 2; ks++){
            int fblk = ((ks*4 + quad) ^ (il & 7)) << 3;
            bf16x8 Af[4], Wf[2];
#pragma unroll
            for (int mt = 0; mt < 4; mt++)
                Af[mt] = *(const bf16x8*)(&At[((wm*64 + mt*16 + il) << 6) + fblk]);
#pragma unroll
            for (int nt = 0; nt < 2; nt++)
                Wf[nt] = *(const bf16x8*)(&Wt[((wn*32 + nt*16 + il) << 6) + fblk]);
#pragma unroll
            for (int mt = 0; mt < 4; mt++)
#pragma unroll
                for (int nt = 0; nt < 2; nt++)
                    acc[mt][nt] = __builtin_amdgcn_mfma_f32_16x16x32_bf16(Af[mt], Wf[nt], acc[mt][nt], 0, 0, 0);
        }
        __syncthreads();
    }
    float bb[2];
#pragma unroll
    for (int nt = 0; nt < 2; nt++) bb[nt] = bias[nbase + wn*32 + nt*16 + il];
#pragma unroll
    for (int mt = 0; mt < 4; mt++)
#pragma unroll
        for (int nt = 0; nt < 2; nt++)
#pragma unroll
            for (int r = 0; r < 4; r++){
                int row = mbase + wm*64 + mt*16 + quad*4 + r;
                int col = nbase + wn*32 + nt*16 + il;
                out[(size_t)row*EMB + col] = acc[mt][nt][r] + bb[nt];
            }
}

extern "C" void kernel_launch(void* const* d_in, const int* in_sizes, int n_in,
                              void* d_out, int out_size, void* d_ws, size_t ws_size,
                              hipStream_t stream){
    const float* values = (const float*)d_in[0];
    const float* keys   = (const float*)d_in[1];
    const float* query  = (const float*)d_in[2];
    const int*   mask   = (const int*)d_in[3];
    const float* W_fc   = (const float*)d_in[4];
    const float* b_fc   = (const float*)d_in[5];
    float* out = (float*)d_out;

    char* ws = (char*)d_ws;
    unsigned short* Qb  = (unsigned short*)(ws);                        // 8 MB
    unsigned short* Kfr = (unsigned short*)(ws + (8ull  << 20));        // 8 MB (fragment order)
    unsigned short* Vfr = (unsigned short*)(ws + (16ull << 20));        // 8 MB (fragment order)
    unsigned short* Wb  = (unsigned short*)(ws + (24ull << 20));        // 2 MB
    unsigned*       Mp  = (unsigned*)      (ws + (26ull << 20));        // 16 MB
    float*          Opf = (float*)         (ws + (42ull << 20));        // 16 MB (fp32 O accum)
    float*          Lpf = (float*)         (ws + (58ull << 20));        // 256 KB -> 58.25 MB total

    prep_all  <<<15376, 256, 0, stream>>>(query, keys, values, mask, W_fc,
                                          Qb, Kfr, Vfr, Wb, Mp, (float4*)Opf);
    flash_attn<<<dim3(16, 32, 2), 256, 0, stream>>>(Qb, Kfr, Vfr, Mp, Opf, Lpf);
    gemm_norm <<<dim3(16, 32), 256, 0, stream>>>(Opf, Lpf, Wb, b_fc, out);
}